// Round 11
// baseline (262.978 us; speedup 1.0000x reference)
//
#include <hip/hip_runtime.h>
#include <hip/hip_fp16.h>
#include <stdint.h>

#define D_FEAT 64
#define CH 4096         // edges per chunk in hist/place
#define BKT_BITS 8      // 256 rows per bucket

// ---------------- bucket histogram per chunk ----------------
__global__ __launch_bounds__(256) void bhist_kernel(const int* __restrict__ rows,
                                                    int* __restrict__ block_hist,
                                                    int n_edges, int nb) {
    __shared__ int cnt[256];
    cnt[threadIdx.x] = 0;
    __syncthreads();
    int beg = blockIdx.x * CH;
    int end = min(beg + CH, n_edges);
    for (int i = beg + threadIdx.x; i < end; i += 256)
        atomicAdd(&cnt[rows[i] >> BKT_BITS], 1);
    __syncthreads();
    if (threadIdx.x < nb)
        block_hist[blockIdx.x * nb + threadIdx.x] = cnt[threadIdx.x];
}

// ---------------- parallel scan: per-bucket column over chunks (nchunks <= 512) ----------------
__global__ __launch_bounds__(256) void bscan1_kernel(int* __restrict__ block_hist,
                                                     int* __restrict__ btot,
                                                     int nchunks, int nb) {
    __shared__ int buf[256];
    int j = blockIdx.x;
    int t = threadIdx.x;
    int c0 = 2 * t, c1 = 2 * t + 1;
    int v0 = (c0 < nchunks) ? block_hist[(size_t)c0 * nb + j] : 0;
    int v1 = (c1 < nchunks) ? block_hist[(size_t)c1 * nb + j] : 0;
    int loc = v0 + v1;
    buf[t] = loc;
    __syncthreads();
    for (int off = 1; off < 256; off <<= 1) {
        int add = (t >= off) ? buf[t - off] : 0;
        __syncthreads();
        buf[t] += add;
        __syncthreads();
    }
    int excl = buf[t] - loc;
    if (c0 < nchunks) block_hist[(size_t)c0 * nb + j] = excl;
    if (c1 < nchunks) block_hist[(size_t)c1 * nb + j] = excl + v0;
    if (t == 255) btot[j] = buf[255];
}

__global__ __launch_bounds__(256) void bscan2_kernel(const int* __restrict__ btot,
                                                     int* __restrict__ bbase, int nb) {
    __shared__ int buf[256];
    int t = threadIdx.x;
    int v = (t < nb) ? btot[t] : 0;
    buf[t] = v;
    __syncthreads();
    for (int off = 1; off < 256; off <<= 1) {
        int add = (t >= off) ? buf[t - off] : 0;
        __syncthreads();
        buf[t] += add;
        __syncthreads();
    }
    if (t < nb) {
        bbase[t] = buf[t] - v;
        if (t == nb - 1) bbase[nb] = buf[t];
    }
}

// ---------------- place edges into bucket-contiguous mid array ----------------
__global__ __launch_bounds__(256) void bplace_kernel(const float* __restrict__ vals,
                                                     const int* __restrict__ rows,
                                                     const int* __restrict__ cols,
                                                     const int* __restrict__ block_hist,
                                                     const int* __restrict__ bbase,
                                                     uint2* __restrict__ mid,
                                                     int n_edges, int nb) {
    __shared__ int cnt[256];
    __shared__ int base[256];
    int t = threadIdx.x;
    cnt[t] = 0;
    if (t < nb) base[t] = bbase[t] + block_hist[(size_t)blockIdx.x * nb + t];
    __syncthreads();
    int beg = blockIdx.x * CH;
    int end = min(beg + CH, n_edges);
    for (int i = beg + t; i < end; i += 256) {
        int r = rows[i];
        int b = r >> BKT_BITS;
        int lrank = atomicAdd(&cnt[b], 1);
        __half hv = __float2half_rn(vals[i]);
        unsigned short vb = *reinterpret_cast<unsigned short*>(&hv);
        uint32_t packed = (uint32_t)(cols[i] & 0xFFFF) | ((uint32_t)vb << 16);
        mid[base[b] + lrank] = make_uint2(packed, (uint32_t)r);
    }
}

// ---------------- per-bucket counting sort by row + fused offs[] (no rank stash) ----------------
__global__ __launch_bounds__(256) void bsort_kernel(const uint2* __restrict__ mid,
                                                    const int* __restrict__ bbase,
                                                    uint32_t* __restrict__ edges,
                                                    int* __restrict__ offs,
                                                    int n_nodes, int nb) {
    __shared__ int cnt[256];
    __shared__ int start[256];
    __shared__ int buf[256];
    int j = blockIdx.x;
    int t = threadIdx.x;
    int lo = bbase[j];
    int hi = bbase[j + 1];
    cnt[t] = 0;
    __syncthreads();
    const uint32_t RMASK = (1u << BKT_BITS) - 1u;
    for (int i = lo + t; i < hi; i += 256)
        atomicAdd(&cnt[mid[i].y & RMASK], 1);
    __syncthreads();
    int v = cnt[t];
    buf[t] = v;
    __syncthreads();
    for (int off = 1; off < 256; off <<= 1) {
        int add = (t >= off) ? buf[t - off] : 0;
        __syncthreads();
        buf[t] += add;
        __syncthreads();
    }
    int st = buf[t] - v;
    start[t] = st;
    int rg = (j << BKT_BITS) + t;
    if (rg <= n_nodes) offs[rg] = lo + st;
    __syncthreads();
    cnt[t] = 0;
    __syncthreads();
    for (int i = lo + t; i < hi; i += 256) {
        uint2 e = mid[i];
        int r = (int)(e.y & RMASK);
        int rank = atomicAdd(&cnt[r], 1);
        edges[lo + start[r] + rank] = e.x;
    }
}

// ---------------- x (f32) -> fp16, same row-major layout ----------------
__global__ __launch_bounds__(256) void xcast_kernel(const float2* __restrict__ x,
                                                    __half2* __restrict__ dst, int total_h2) {
    int t = blockIdx.x * 256 + threadIdx.x;
    if (t >= total_h2) return;
    dst[t] = __float22half2_rn(x[t]);
}

// ---------------- SpMM: 2 rows per wave (32 lanes each), fp16 in, 16-deep gathers ------

__device__ __forceinline__ float unpack_val(uint32_t u) {
    __half_raw hr;
    hr.x = (unsigned short)(u >> 16);
    return __half2float(__half(hr));
}

template <int K>
__device__ __forceinline__ void gfma2h(const __half2* __restrict__ hv,
                                       const uint32_t* __restrict__ edges,
                                       int j, int gl, float2& acc) {
    uint32_t u[K];
#pragma unroll
    for (int k = 0; k < K; ++k) u[k] = __builtin_nontemporal_load(&edges[j + k]);
    float2 hh[K];
#pragma unroll
    for (int k = 0; k < K; ++k)
        hh[k] = __half22float2(hv[(size_t)(u[k] & 0xFFFF) * 32 + gl]);
#pragma unroll
    for (int k = 0; k < K; ++k) {
        float v = unpack_val(u[k]);
        acc.x = fmaf(v, hh[k].x, acc.x);
        acc.y = fmaf(v, hh[k].y, acc.y);
    }
}

template <bool OUT_F32>
__global__ __launch_bounds__(256) void spmm_h_kernel(const __half2* __restrict__ hv,
                                                     const uint32_t* __restrict__ edges,
                                                     const int* __restrict__ offs,
                                                     void* __restrict__ outv, int n_nodes) {
    int wave = (int)(((long long)blockIdx.x * blockDim.x + threadIdx.x) >> 6);
    int lane = threadIdx.x & 63;
    int g = lane >> 5;       // which row of the pair
    int gl = lane & 31;      // half2 index; features (2gl, 2gl+1)
    int row = wave * 2 + g;
    if (row >= n_nodes) return;
    int beg = offs[row];
    int end = offs[row + 1];
    float2 acc = make_float2(0.f, 0.f);
    int j = beg;
    // 16 gathers in flight
    for (; j + 16 <= end; j += 16) {
        gfma2h<8>(hv, edges, j, gl, acc);
        gfma2h<8>(hv, edges, j + 8, gl, acc);
    }
    if (j + 8 <= end) { gfma2h<8>(hv, edges, j, gl, acc); j += 8; }
    if (j + 4 <= end) { gfma2h<4>(hv, edges, j, gl, acc); j += 4; }
    for (; j < end; ++j) {
        uint32_t u = __builtin_nontemporal_load(&edges[j]);
        float2 hh = __half22float2(hv[(size_t)(u & 0xFFFF) * 32 + gl]);
        float v = unpack_val(u);
        acc.x = fmaf(v, hh.x, acc.x);
        acc.y = fmaf(v, hh.y, acc.y);
    }
    if (OUT_F32) {
        ((float2*)outv)[(size_t)row * 32 + gl] = acc;
    } else {
        ((__half2*)outv)[(size_t)row * 32 + gl] = __float22half2_rn(acc);
    }
}

// ---------------- fallback (atomic path) ----------------

__global__ void spmm_atomic_kernel(const float* __restrict__ h,
                                   const float* __restrict__ vals,
                                   const int* __restrict__ rows,
                                   const int* __restrict__ cols,
                                   float* __restrict__ out,
                                   int n_edges) {
    long long tid = (long long)blockIdx.x * blockDim.x + threadIdx.x;
    int e = (int)(tid >> 6);
    int d = (int)(tid & 63);
    if (e >= n_edges) return;
    float m = vals[e] * h[(size_t)cols[e] * D_FEAT + d];
    atomicAdd(&out[(size_t)rows[e] * D_FEAT + d], m);
}

extern "C" void kernel_launch(void* const* d_in, const int* in_sizes, int n_in,
                              void* d_out, int out_size, void* d_ws, size_t ws_size,
                              hipStream_t stream) {
    const float* x    = (const float*)d_in[0];
    const float* vals = (const float*)d_in[1];
    const int*   rows = (const int*)d_in[2];
    const int*   cols = (const int*)d_in[3];

    int n_nodes = in_sizes[0] / D_FEAT;
    int n_edges = in_sizes[1];

    float* out = (float*)d_out;

    size_t buf_bytes_f32 = (size_t)n_nodes * D_FEAT * sizeof(float);
    size_t buf_bytes_f16 = (size_t)n_nodes * D_FEAT * sizeof(__half);

    auto align_up = [](size_t v) { return (v + 255) & ~(size_t)255; };

    int nb = (n_nodes + 255) >> BKT_BITS;
    int nchunks = (n_edges + CH - 1) / CH;

    size_t pa_b   = align_up(buf_bytes_f16);
    size_t pb_b   = align_up(buf_bytes_f16);
    size_t mid_b  = align_up((size_t)n_edges * sizeof(uint2));
    size_t region1 = pa_b + pb_b;
    if (mid_b > region1) region1 = mid_b;          // mid aliases pA/pB (dead before xcast/spmm)
    size_t edges_b = align_up((size_t)n_edges * sizeof(uint32_t));
    size_t offs_b  = align_up((size_t)(n_nodes + 1) * sizeof(int));
    size_t bh_b    = align_up((size_t)nchunks * nb * sizeof(int));
    size_t bb_b    = align_up((size_t)(nb + 1) * sizeof(int));
    size_t bt_b    = align_up(256 * sizeof(int));
    size_t need = region1 + edges_b + offs_b + bh_b + bb_b + bt_b;

    if (ws_size < need || n_nodes > 65536 || nchunks > 512) {
        float* ws = (float*)d_ws;
        float* dsts[5] = {out, ws, out, ws, out};
        long long total_threads = (long long)n_edges * D_FEAT;
        int block = 256;
        int grid = (int)((total_threads + block - 1) / block);
        const float* src = x;
        for (int s = 0; s < 5; ++s) {
            hipMemsetAsync(dsts[s], 0, buf_bytes_f32, stream);
            spmm_atomic_kernel<<<grid, block, 0, stream>>>(src, vals, rows, cols,
                                                           dsts[s], n_edges);
            src = dsts[s];
        }
        return;
    }

    char* p = (char*)d_ws;
    char* r1 = p;                        p += region1;
    uint32_t* edges      = (uint32_t*)p; p += edges_b;
    int*      offs       = (int*)p;      p += offs_b;
    int*      block_hist = (int*)p;      p += bh_b;
    int*      bbase      = (int*)p;      p += bb_b;
    int*      btot       = (int*)p;      p += bt_b;

    __half2* pA = (__half2*)r1;
    __half2* pB = (__half2*)(r1 + pa_b);
    uint2*   mid = (uint2*)r1;           // aliases pA/pB; consumed before they're written

    // ---- build row-sorted packed edge list + offs ----
    bhist_kernel<<<nchunks, 256, 0, stream>>>(rows, block_hist, n_edges, nb);
    bscan1_kernel<<<nb, 256, 0, stream>>>(block_hist, btot, nchunks, nb);
    bscan2_kernel<<<1, 256, 0, stream>>>(btot, bbase, nb);
    bplace_kernel<<<nchunks, 256, 0, stream>>>(vals, rows, cols, block_hist, bbase,
                                               mid, n_edges, nb);
    bsort_kernel<<<nb, 256, 0, stream>>>(mid, bbase, edges, offs, n_nodes, nb);

    // ---- x -> fp16 once, then 5 fp16 SpMM steps ----
    {
        int total_h2 = n_nodes * 32;
        xcast_kernel<<<(total_h2 + 255) / 256, 256, 0, stream>>>((const float2*)x, pA, total_h2);

        int rows_per_block = 8;  // 4 waves x 2 rows
        int grid = (n_nodes + rows_per_block - 1) / rows_per_block;
        // pA -> pB -> pA -> pB -> pA -> out(f32)
        spmm_h_kernel<false><<<grid, 256, 0, stream>>>(pA, edges, offs, pB, n_nodes);
        spmm_h_kernel<false><<<grid, 256, 0, stream>>>(pB, edges, offs, pA, n_nodes);
        spmm_h_kernel<false><<<grid, 256, 0, stream>>>(pA, edges, offs, pB, n_nodes);
        spmm_h_kernel<false><<<grid, 256, 0, stream>>>(pB, edges, offs, pA, n_nodes);
        spmm_h_kernel<true ><<<grid, 256, 0, stream>>>(pA, edges, offs, out, n_nodes);
    }
}

// Round 12
// 236.430 us; speedup vs baseline: 1.1123x; 1.1123x over previous
//
#include <hip/hip_runtime.h>
#include <hip/hip_fp16.h>
#include <stdint.h>

#define D_FEAT 64
#define CH 4096         // edges per chunk in hist/place
#define BKT_BITS 8      // 256 rows per bucket

// ---------------- bucket histogram per chunk ----------------
__global__ __launch_bounds__(256) void bhist_kernel(const int* __restrict__ rows,
                                                    int* __restrict__ block_hist,
                                                    int n_edges, int nb) {
    __shared__ int cnt[256];
    cnt[threadIdx.x] = 0;
    __syncthreads();
    int beg = blockIdx.x * CH;
    int end = min(beg + CH, n_edges);
    for (int i = beg + threadIdx.x; i < end; i += 256)
        atomicAdd(&cnt[rows[i] >> BKT_BITS], 1);
    __syncthreads();
    if (threadIdx.x < nb)
        block_hist[blockIdx.x * nb + threadIdx.x] = cnt[threadIdx.x];
}

// ---------------- parallel scan: per-bucket column over chunks (nchunks <= 512) ----------------
__global__ __launch_bounds__(256) void bscan1_kernel(int* __restrict__ block_hist,
                                                     int* __restrict__ btot,
                                                     int nchunks, int nb) {
    __shared__ int buf[256];
    int j = blockIdx.x;
    int t = threadIdx.x;
    int c0 = 2 * t, c1 = 2 * t + 1;
    int v0 = (c0 < nchunks) ? block_hist[(size_t)c0 * nb + j] : 0;
    int v1 = (c1 < nchunks) ? block_hist[(size_t)c1 * nb + j] : 0;
    int loc = v0 + v1;
    buf[t] = loc;
    __syncthreads();
    for (int off = 1; off < 256; off <<= 1) {
        int add = (t >= off) ? buf[t - off] : 0;
        __syncthreads();
        buf[t] += add;
        __syncthreads();
    }
    int excl = buf[t] - loc;
    if (c0 < nchunks) block_hist[(size_t)c0 * nb + j] = excl;
    if (c1 < nchunks) block_hist[(size_t)c1 * nb + j] = excl + v0;
    if (t == 255) btot[j] = buf[255];
}

__global__ __launch_bounds__(256) void bscan2_kernel(const int* __restrict__ btot,
                                                     int* __restrict__ bbase, int nb) {
    __shared__ int buf[256];
    int t = threadIdx.x;
    int v = (t < nb) ? btot[t] : 0;
    buf[t] = v;
    __syncthreads();
    for (int off = 1; off < 256; off <<= 1) {
        int add = (t >= off) ? buf[t - off] : 0;
        __syncthreads();
        buf[t] += add;
        __syncthreads();
    }
    if (t < nb) {
        bbase[t] = buf[t] - v;
        if (t == nb - 1) bbase[nb] = buf[t];
    }
}

// ---------------- place edges into bucket-contiguous mid array ----------------
__global__ __launch_bounds__(256) void bplace_kernel(const float* __restrict__ vals,
                                                     const int* __restrict__ rows,
                                                     const int* __restrict__ cols,
                                                     const int* __restrict__ block_hist,
                                                     const int* __restrict__ bbase,
                                                     uint2* __restrict__ mid,
                                                     int n_edges, int nb) {
    __shared__ int cnt[256];
    __shared__ int base[256];
    int t = threadIdx.x;
    cnt[t] = 0;
    if (t < nb) base[t] = bbase[t] + block_hist[(size_t)blockIdx.x * nb + t];
    __syncthreads();
    int beg = blockIdx.x * CH;
    int end = min(beg + CH, n_edges);
    for (int i = beg + t; i < end; i += 256) {
        int r = rows[i];
        int b = r >> BKT_BITS;
        int lrank = atomicAdd(&cnt[b], 1);
        __half hv = __float2half_rn(vals[i]);
        unsigned short vb = *reinterpret_cast<unsigned short*>(&hv);
        uint32_t packed = (uint32_t)(cols[i] & 0xFFFF) | ((uint32_t)vb << 16);
        mid[base[b] + lrank] = make_uint2(packed, (uint32_t)r);
    }
}

// ---------------- per-bucket counting sort by row + fused offs[] (no rank stash) ----------------
__global__ __launch_bounds__(256) void bsort_kernel(const uint2* __restrict__ mid,
                                                    const int* __restrict__ bbase,
                                                    uint32_t* __restrict__ edges,
                                                    int* __restrict__ offs,
                                                    int n_nodes, int nb) {
    __shared__ int cnt[256];
    __shared__ int start[256];
    __shared__ int buf[256];
    int j = blockIdx.x;
    int t = threadIdx.x;
    int lo = bbase[j];
    int hi = bbase[j + 1];
    cnt[t] = 0;
    __syncthreads();
    const uint32_t RMASK = (1u << BKT_BITS) - 1u;
    for (int i = lo + t; i < hi; i += 256)
        atomicAdd(&cnt[mid[i].y & RMASK], 1);
    __syncthreads();
    int v = cnt[t];
    buf[t] = v;
    __syncthreads();
    for (int off = 1; off < 256; off <<= 1) {
        int add = (t >= off) ? buf[t - off] : 0;
        __syncthreads();
        buf[t] += add;
        __syncthreads();
    }
    int st = buf[t] - v;
    start[t] = st;
    int rg = (j << BKT_BITS) + t;
    if (rg <= n_nodes) offs[rg] = lo + st;
    __syncthreads();
    cnt[t] = 0;
    __syncthreads();
    for (int i = lo + t; i < hi; i += 256) {
        uint2 e = mid[i];
        int r = (int)(e.y & RMASK);
        int rank = atomicAdd(&cnt[r], 1);
        edges[lo + start[r] + rank] = e.x;
    }
}

// ---------------- x (f32) -> fp16, same row-major layout ----------------
__global__ __launch_bounds__(256) void xcast_kernel(const float2* __restrict__ x,
                                                    __half2* __restrict__ dst, int total_h2) {
    int t = blockIdx.x * 256 + threadIdx.x;
    if (t >= total_h2) return;
    dst[t] = __float22half2_rn(x[t]);
}

// ---------------- SpMM: 2 rows per wave (32 lanes each), fp16 in, 8-deep gathers ------

__device__ __forceinline__ float unpack_val(uint32_t u) {
    __half_raw hr;
    hr.x = (unsigned short)(u >> 16);
    return __half2float(__half(hr));
}

template <int K>
__device__ __forceinline__ void gfma2h(const __half2* __restrict__ hv,
                                       const uint32_t* __restrict__ edges,
                                       int j, int gl, float2& acc) {
    uint32_t u[K];
#pragma unroll
    for (int k = 0; k < K; ++k) u[k] = edges[j + k];
    float2 hh[K];
#pragma unroll
    for (int k = 0; k < K; ++k)
        hh[k] = __half22float2(hv[(size_t)(u[k] & 0xFFFF) * 32 + gl]);
#pragma unroll
    for (int k = 0; k < K; ++k) {
        float v = unpack_val(u[k]);
        acc.x = fmaf(v, hh[k].x, acc.x);
        acc.y = fmaf(v, hh[k].y, acc.y);
    }
}

template <bool OUT_F32>
__global__ __launch_bounds__(256) void spmm_h_kernel(const __half2* __restrict__ hv,
                                                     const uint32_t* __restrict__ edges,
                                                     const int* __restrict__ offs,
                                                     void* __restrict__ outv, int n_nodes) {
    int wave = (int)(((long long)blockIdx.x * blockDim.x + threadIdx.x) >> 6);
    int lane = threadIdx.x & 63;
    int g = lane >> 5;       // which row of the pair
    int gl = lane & 31;      // half2 index; features (2gl, 2gl+1)
    int row = wave * 2 + g;
    if (row >= n_nodes) return;
    int beg = offs[row];
    int end = offs[row + 1];
    float2 acc = make_float2(0.f, 0.f);
    int j = beg;
    for (; j + 8 <= end; j += 8) gfma2h<8>(hv, edges, j, gl, acc);
    if (j + 4 <= end) { gfma2h<4>(hv, edges, j, gl, acc); j += 4; }
    for (; j < end; ++j) {
        uint32_t u = edges[j];
        float2 hh = __half22float2(hv[(size_t)(u & 0xFFFF) * 32 + gl]);
        float v = unpack_val(u);
        acc.x = fmaf(v, hh.x, acc.x);
        acc.y = fmaf(v, hh.y, acc.y);
    }
    if (OUT_F32) {
        ((float2*)outv)[(size_t)row * 32 + gl] = acc;
    } else {
        ((__half2*)outv)[(size_t)row * 32 + gl] = __float22half2_rn(acc);
    }
}

// ---------------- fallback (atomic path) ----------------

__global__ void spmm_atomic_kernel(const float* __restrict__ h,
                                   const float* __restrict__ vals,
                                   const int* __restrict__ rows,
                                   const int* __restrict__ cols,
                                   float* __restrict__ out,
                                   int n_edges) {
    long long tid = (long long)blockIdx.x * blockDim.x + threadIdx.x;
    int e = (int)(tid >> 6);
    int d = (int)(tid & 63);
    if (e >= n_edges) return;
    float m = vals[e] * h[(size_t)cols[e] * D_FEAT + d];
    atomicAdd(&out[(size_t)rows[e] * D_FEAT + d], m);
}

extern "C" void kernel_launch(void* const* d_in, const int* in_sizes, int n_in,
                              void* d_out, int out_size, void* d_ws, size_t ws_size,
                              hipStream_t stream) {
    const float* x    = (const float*)d_in[0];
    const float* vals = (const float*)d_in[1];
    const int*   rows = (const int*)d_in[2];
    const int*   cols = (const int*)d_in[3];

    int n_nodes = in_sizes[0] / D_FEAT;
    int n_edges = in_sizes[1];

    float* out = (float*)d_out;

    size_t buf_bytes_f32 = (size_t)n_nodes * D_FEAT * sizeof(float);
    size_t buf_bytes_f16 = (size_t)n_nodes * D_FEAT * sizeof(__half);

    auto align_up = [](size_t v) { return (v + 255) & ~(size_t)255; };

    int nb = (n_nodes + 255) >> BKT_BITS;
    int nchunks = (n_edges + CH - 1) / CH;

    size_t pa_b   = align_up(buf_bytes_f16);
    size_t pb_b   = align_up(buf_bytes_f16);
    size_t mid_b  = align_up((size_t)n_edges * sizeof(uint2));
    size_t region1 = pa_b + pb_b;
    if (mid_b > region1) region1 = mid_b;          // mid aliases pA/pB (dead before xcast/spmm)
    size_t edges_b = align_up((size_t)n_edges * sizeof(uint32_t));
    size_t offs_b  = align_up((size_t)(n_nodes + 1) * sizeof(int));
    size_t bh_b    = align_up((size_t)nchunks * nb * sizeof(int));
    size_t bb_b    = align_up((size_t)(nb + 1) * sizeof(int));
    size_t bt_b    = align_up(256 * sizeof(int));
    size_t need = region1 + edges_b + offs_b + bh_b + bb_b + bt_b;

    if (ws_size < need || n_nodes > 65536 || nchunks > 512) {
        float* ws = (float*)d_ws;
        float* dsts[5] = {out, ws, out, ws, out};
        long long total_threads = (long long)n_edges * D_FEAT;
        int block = 256;
        int grid = (int)((total_threads + block - 1) / block);
        const float* src = x;
        for (int s = 0; s < 5; ++s) {
            hipMemsetAsync(dsts[s], 0, buf_bytes_f32, stream);
            spmm_atomic_kernel<<<grid, block, 0, stream>>>(src, vals, rows, cols,
                                                           dsts[s], n_edges);
            src = dsts[s];
        }
        return;
    }

    char* p = (char*)d_ws;
    char* r1 = p;                        p += region1;
    uint32_t* edges      = (uint32_t*)p; p += edges_b;
    int*      offs       = (int*)p;      p += offs_b;
    int*      block_hist = (int*)p;      p += bh_b;
    int*      bbase      = (int*)p;      p += bb_b;
    int*      btot       = (int*)p;      p += bt_b;

    __half2* pA = (__half2*)r1;
    __half2* pB = (__half2*)(r1 + pa_b);
    uint2*   mid = (uint2*)r1;           // aliases pA/pB; consumed before they're written

    // ---- build row-sorted packed edge list + offs ----
    bhist_kernel<<<nchunks, 256, 0, stream>>>(rows, block_hist, n_edges, nb);
    bscan1_kernel<<<nb, 256, 0, stream>>>(block_hist, btot, nchunks, nb);
    bscan2_kernel<<<1, 256, 0, stream>>>(btot, bbase, nb);
    bplace_kernel<<<nchunks, 256, 0, stream>>>(vals, rows, cols, block_hist, bbase,
                                               mid, n_edges, nb);
    bsort_kernel<<<nb, 256, 0, stream>>>(mid, bbase, edges, offs, n_nodes, nb);

    // ---- x -> fp16 once, then 5 fp16 SpMM steps ----
    {
        int total_h2 = n_nodes * 32;
        xcast_kernel<<<(total_h2 + 255) / 256, 256, 0, stream>>>((const float2*)x, pA, total_h2);

        int rows_per_block = 8;  // 4 waves x 2 rows
        int grid = (n_nodes + rows_per_block - 1) / rows_per_block;
        // pA -> pB -> pA -> pB -> pA -> out(f32)
        spmm_h_kernel<false><<<grid, 256, 0, stream>>>(pA, edges, offs, pB, n_nodes);
        spmm_h_kernel<false><<<grid, 256, 0, stream>>>(pB, edges, offs, pA, n_nodes);
        spmm_h_kernel<false><<<grid, 256, 0, stream>>>(pA, edges, offs, pB, n_nodes);
        spmm_h_kernel<false><<<grid, 256, 0, stream>>>(pB, edges, offs, pA, n_nodes);
        spmm_h_kernel<true ><<<grid, 256, 0, stream>>>(pA, edges, offs, out, n_nodes);
    }
}